// Round 1
// baseline (467.806 us; speedup 1.0000x reference)
//
#include <hip/hip_runtime.h>
#include <cmath>

// ---------------------------------------------------------------------------
// GAT layer: N=100000 nodes, IN=128, OUT=32, H=4 (H*OUT=128), E=1.6M edges.
// Pipeline:
//   K1  k_gemm    : xw = x@W  [N,128], fused a_src/a_dst logits [N,4]
//   K2a k_hist    : histogram of dst degrees (incl. self loops)
//   K2b scan1/2/3 : exclusive prefix sum -> CSR offsets + cursor
//   K2c k_scatter : bucket src indices by dst (CSR edge list)
//   K3  k_agg     : per-dst-node wave: online segment-softmax + weighted
//                   aggregation of xw[src], bias + ELU, single write of out row
// ---------------------------------------------------------------------------

__device__ __forceinline__ int blockInclScan(int v, int tid, int* lds) {
  int lane = tid & 63;
  int wid = tid >> 6;
#pragma unroll
  for (int off = 1; off < 64; off <<= 1) {
    int t = __shfl_up(v, off);
    if (lane >= off) v += t;
  }
  if (lane == 63) lds[wid] = v;
  __syncthreads();
  int add = 0;
  for (int i = 0; i < wid; ++i) add += lds[i];
  v += add;
  __syncthreads();
  return v;
}

// ---------------- K1: GEMM + attention logits ----------------
// grid (ceil(N/128), 2), block 128.  tx = tid&7 (8 col-groups of 8),
// ty = tid>>3 (16 row-groups of 8).  Each block: 128 rows x 64 cols (one
// col-half = 2 heads).  k-chunked by 32.  8x8 register tile per thread.
__global__ __launch_bounds__(128) void k_gemm(
    const float* __restrict__ x, const float* __restrict__ Wm,
    const float* __restrict__ att_src, const float* __restrict__ att_dst,
    float* __restrict__ xw, float* __restrict__ a_src, float* __restrict__ a_dst,
    int N) {
  __shared__ float xs[128][36];  // [row][k in chunk], pad 36 for bank spread
  __shared__ float Wl[32][64];   // [k in chunk][col in half]
  const int tid = threadIdx.x;
  const int tx = tid & 7;
  const int ty = tid >> 3;
  const int ch = blockIdx.y;  // column half (heads 0-1 or 2-3)
  const int row0 = blockIdx.x * 128;

  float acc[8][8];
#pragma unroll
  for (int r = 0; r < 8; ++r)
#pragma unroll
    for (int c = 0; c < 8; ++c) acc[r][c] = 0.f;

  for (int kc = 0; kc < 4; ++kc) {
    __syncthreads();
    // stage x chunk: 128 rows x 32 k = 1024 float4, 8 per thread
#pragma unroll
    for (int j = 0; j < 8; ++j) {
      int f = tid + j * 128;
      int r = f >> 3, k4 = f & 7;
      int row = row0 + r;
      float4 v = make_float4(0.f, 0.f, 0.f, 0.f);
      if (row < N) v = *(const float4*)&x[(size_t)row * 128 + kc * 32 + k4 * 4];
      *(float4*)&xs[r][k4 * 4] = v;
    }
    // stage W chunk: 32 k x 64 cols = 512 float4, 4 per thread
#pragma unroll
    for (int j = 0; j < 4; ++j) {
      int f = tid + j * 128;
      int kr = f >> 4, c4 = f & 15;
      *(float4*)&Wl[kr][c4 * 4] =
          *(const float4*)&Wm[(size_t)(kc * 32 + kr) * 128 + ch * 64 + c4 * 4];
    }
    __syncthreads();
#pragma unroll 4
    for (int k = 0; k < 32; ++k) {
      float wv[8];
      *(float4*)&wv[0] = *(const float4*)&Wl[k][tx * 8];
      *(float4*)&wv[4] = *(const float4*)&Wl[k][tx * 8 + 4];
      float xv[8];
#pragma unroll
      for (int r = 0; r < 8; ++r) xv[r] = xs[ty * 8 + r][k];
#pragma unroll
      for (int r = 0; r < 8; ++r)
#pragma unroll
        for (int c = 0; c < 8; ++c) acc[r][c] = fmaf(xv[r], wv[c], acc[r][c]);
    }
  }

  float att_s[8], att_d[8];
#pragma unroll
  for (int c = 0; c < 8; ++c) {
    att_s[c] = att_src[ch * 64 + tx * 8 + c];
    att_d[c] = att_dst[ch * 64 + tx * 8 + c];
  }

#pragma unroll
  for (int r = 0; r < 8; ++r) {
    int row = row0 + ty * 8 + r;
    bool ok = row < N;
    float vs = 0.f, vd = 0.f;
#pragma unroll
    for (int c = 0; c < 8; ++c) {
      vs += acc[r][c] * att_s[c];
      vd += acc[r][c] * att_d[c];
    }
    // reduce across the 4 tx-lanes (32 cols) of each head
    vs += __shfl_xor(vs, 1);
    vs += __shfl_xor(vs, 2);
    vd += __shfl_xor(vd, 1);
    vd += __shfl_xor(vd, 2);
    if (ok) {
      *(float4*)&xw[(size_t)row * 128 + ch * 64 + tx * 8] =
          make_float4(acc[r][0], acc[r][1], acc[r][2], acc[r][3]);
      *(float4*)&xw[(size_t)row * 128 + ch * 64 + tx * 8 + 4] =
          make_float4(acc[r][4], acc[r][5], acc[r][6], acc[r][7]);
      if ((tx & 3) == 0) {
        a_src[row * 4 + ch * 2 + (tx >> 2)] = vs;
        a_dst[row * 4 + ch * 2 + (tx >> 2)] = vd;
      }
    }
  }
}

// ---------------- K2: CSR build ----------------
__global__ __launch_bounds__(256) void k_hist(const int* __restrict__ ei, int E,
                                              int N, int* __restrict__ deg) {
  int e = blockIdx.x * 256 + threadIdx.x;
  if (e >= E + N) return;
  int dst = (e < E) ? ei[E + e] : (e - E);
  atomicAdd(&deg[dst], 1);
}

__global__ __launch_bounds__(256) void k_scan1(const int* __restrict__ deg,
                                               int* __restrict__ offs,
                                               int* __restrict__ part, int N) {
  __shared__ int lds[4];
  int i = blockIdx.x * 256 + threadIdx.x;
  int v = (i < N) ? deg[i] : 0;
  int s = blockInclScan(v, threadIdx.x, lds);
  if (i < N) offs[i + 1] = s;
  if (threadIdx.x == 255) part[blockIdx.x] = s;
}

__global__ __launch_bounds__(256) void k_scan2(int* part, int B) {
  __shared__ int lds[4];
  __shared__ int basesh;
  int tid = threadIdx.x;
  int base = 0;
  for (int c0 = 0; c0 < B; c0 += 256) {
    int i = c0 + tid;
    int v = (i < B) ? part[i] : 0;
    int sv = blockInclScan(v, tid, lds);
    if (i < B) part[i] = base + sv;
    if (tid == 255) basesh = base + sv;
    __syncthreads();
    base = basesh;
    __syncthreads();
  }
}

__global__ __launch_bounds__(256) void k_scan3(const int* __restrict__ deg,
                                               int* __restrict__ offs,
                                               const int* __restrict__ part,
                                               int* __restrict__ cursor, int N) {
  int i = blockIdx.x * 256 + threadIdx.x;
  int add = blockIdx.x ? part[blockIdx.x - 1] : 0;
  if (i < N) {
    int inc = offs[i + 1] + add;
    offs[i + 1] = inc;
    cursor[i] = inc - deg[i];  // exclusive prefix = segment start
  }
  if (i == 0) offs[0] = 0;
}

__global__ __launch_bounds__(256) void k_scatter(const int* __restrict__ ei, int E,
                                                 int N, int* __restrict__ cursor,
                                                 int* __restrict__ srcs) {
  int e = blockIdx.x * 256 + threadIdx.x;
  if (e >= E + N) return;
  int src, dst;
  if (e < E) {
    src = ei[e];
    dst = ei[E + e];
  } else {
    src = e - E;
    dst = e - E;
  }
  int pos = atomicAdd(&cursor[dst], 1);
  srcs[pos] = src;
}

// ---------------- K3: per-node online softmax + aggregate ----------------
// one 64-lane wave per destination node; lane covers 2 channels.
__global__ __launch_bounds__(256) void k_agg(
    const int* __restrict__ srcs, const int* __restrict__ offs,
    const float* __restrict__ xw, const float* __restrict__ asrc,
    const float* __restrict__ adst, const float* __restrict__ bias,
    float* __restrict__ out, int N) {
  int gw = (int)(((size_t)blockIdx.x * blockDim.x + threadIdx.x) >> 6);
  int lane = threadIdx.x & 63;
  if (gw >= N) return;
  int beg = offs[gw];
  int end = offs[gw + 1];
  int h = lane >> 4;  // head of this lane's 2 channels (cols 2l, 2l+1)
  float ad = adst[gw * 4 + h];
  float m = -INFINITY, s = 0.f, a0 = 0.f, a1 = 0.f;
  for (int i = beg; i < end; ++i) {
    int src = srcs[i];
    float z = asrc[src * 4 + h] + ad;
    z = z > 0.f ? z : 0.2f * z;  // leaky_relu 0.2
    float mn = fmaxf(m, z);
    float c = expf(m - mn);  // first iter: exp(-inf)=0
    float p = expf(z - mn);
    float2 xv = *(const float2*)&xw[(size_t)src * 128 + lane * 2];
    s = s * c + p;
    a0 = fmaf(a0, c, p * xv.x);
    a1 = fmaf(a1, c, p * xv.y);
    m = mn;
  }
  float inv = 1.f / s;  // s >= 1 (max term contributes exp(0)=1)
  float o0 = a0 * inv + bias[lane * 2];
  float o1 = a1 * inv + bias[lane * 2 + 1];
  o0 = o0 > 0.f ? o0 : expm1f(o0);  // ELU
  o1 = o1 > 0.f ? o1 : expm1f(o1);
  *(float2*)&out[(size_t)gw * 128 + lane * 2] = make_float2(o0, o1);
}

// ---------------------------------------------------------------------------
extern "C" void kernel_launch(void* const* d_in, const int* in_sizes, int n_in,
                              void* d_out, int out_size, void* d_ws, size_t ws_size,
                              hipStream_t stream) {
  const float* x = (const float*)d_in[0];
  const int* ei = (const int*)d_in[1];  // [2,E] int
  const float* Wm = (const float*)d_in[2];
  const float* att_src = (const float*)d_in[3];
  const float* att_dst = (const float*)d_in[4];
  const float* bias = (const float*)d_in[5];
  float* out = (float*)d_out;

  const int N = in_sizes[0] / 128;
  const int E = in_sizes[1] / 2;
  const int EL = E + N;  // edges + self loops

  size_t off = 0;
  auto carve = [&](size_t bytes) -> void* {
    void* p = (char*)d_ws + off;
    off += (bytes + 255) & ~(size_t)255;
    return p;
  };
  float* xw = (float*)carve((size_t)N * 128 * 4);
  float* a_src = (float*)carve((size_t)N * 4 * 4);
  float* a_dst = (float*)carve((size_t)N * 4 * 4);
  int* deg = (int*)carve((size_t)N * 4);
  int* offs = (int*)carve((size_t)(N + 1) * 4);
  int* cursor = (int*)carve((size_t)N * 4);
  int* part = (int*)carve(4096);
  int* srcs = (int*)carve((size_t)EL * 4);

  hipMemsetAsync(deg, 0, (size_t)N * 4, stream);

  dim3 g1((N + 127) / 128, 2);
  k_gemm<<<g1, 128, 0, stream>>>(x, Wm, att_src, att_dst, xw, a_src, a_dst, N);

  int ebl = (EL + 255) / 256;
  k_hist<<<ebl, 256, 0, stream>>>(ei, E, N, deg);

  int B = (N + 255) / 256;
  k_scan1<<<B, 256, 0, stream>>>(deg, offs, part, N);
  k_scan2<<<1, 256, 0, stream>>>(part, B);
  k_scan3<<<B, 256, 0, stream>>>(deg, offs, part, cursor, N);

  k_scatter<<<ebl, 256, 0, stream>>>(ei, E, N, cursor, srcs);

  int abl = (int)(((size_t)N * 64 + 255) / 256);
  k_agg<<<abl, 256, 0, stream>>>(srcs, offs, xw, a_src, a_dst, bias, out, N);
}

// Round 2
// 421.609 us; speedup vs baseline: 1.1096x; 1.1096x over previous
//
#include <hip/hip_runtime.h>
#include <cmath>

// ---------------------------------------------------------------------------
// GAT layer: N=100000 nodes, IN=128, OUT=32, H=4 (H*OUT=128), E=1.6M edges.
// Pipeline:
//   K1  k_gemm    : xw = x@W  [N,128], fused a_src/a_dst logits [N,4]
//                   (logits pre-scaled by log2(e) so k_agg can use v_exp_f32)
//   K2a k_hist    : histogram of dst degrees (incl. self loops)
//   K2b scan1/2/3 : exclusive prefix sum -> CSR offsets + cursor
//   K2c k_scatter : bucket src indices by dst (CSR edge list)
//   K3  k_agg     : per-dst-node wave: segment softmax (no max-subtraction --
//                   logits bounded ~|5|, exp ratio identical) + weighted
//                   aggregation of xw[src], bias + ELU, single write of out row
// ---------------------------------------------------------------------------

#define LOG2E 1.44269504088896340736f

__device__ __forceinline__ float fast_exp2(float x) {
#if __has_builtin(__builtin_amdgcn_exp2f)
  return __builtin_amdgcn_exp2f(x);
#else
  return exp2f(x);
#endif
}

__device__ __forceinline__ int blockInclScan(int v, int tid, int* lds) {
  int lane = tid & 63;
  int wid = tid >> 6;
#pragma unroll
  for (int off = 1; off < 64; off <<= 1) {
    int t = __shfl_up(v, off);
    if (lane >= off) v += t;
  }
  if (lane == 63) lds[wid] = v;
  __syncthreads();
  int add = 0;
  for (int i = 0; i < wid; ++i) add += lds[i];
  v += add;
  __syncthreads();
  return v;
}

// ---------------- K1: GEMM + attention logits ----------------
// grid (ceil(N/128), 2), block 128.  tx = tid&7 (8 col-groups of 8),
// ty = tid>>3 (16 row-groups of 8).  Each block: 128 rows x 64 cols (one
// col-half = 2 heads).  k-chunked by 32.  8x8 register tile per thread.
// x staged K-MAJOR (xs_t[k][row]) so per-k fragment reads are 2x ds_read_b128
// (2-way bank aliasing = free) instead of 8x 8-way-conflicted ds_read_b32.
__global__ __launch_bounds__(128) void k_gemm(
    const float* __restrict__ x, const float* __restrict__ Wm,
    const float* __restrict__ att_src, const float* __restrict__ att_dst,
    float* __restrict__ xw, float* __restrict__ a_src, float* __restrict__ a_dst,
    int N) {
  __shared__ float xs_t[32][132];  // [k in chunk][row], pad 132 (16B-aligned rows)
  __shared__ float Wl[32][64];     // [k in chunk][col in half]
  const int tid = threadIdx.x;
  const int tx = tid & 7;
  const int ty = tid >> 3;
  const int ch = blockIdx.y;  // column half (heads 0-1 or 2-3)
  const int row0 = blockIdx.x * 128;

  float acc[8][8];
#pragma unroll
  for (int r = 0; r < 8; ++r)
#pragma unroll
    for (int c = 0; c < 8; ++c) acc[r][c] = 0.f;

  for (int kc = 0; kc < 4; ++kc) {
    __syncthreads();
    // stage x chunk: 128 rows x 32 k = 1024 float4 loads, stored transposed
#pragma unroll
    for (int j = 0; j < 8; ++j) {
      int f = tid + j * 128;
      int r = f >> 3, k4 = f & 7;
      int row = row0 + r;
      float4 v = make_float4(0.f, 0.f, 0.f, 0.f);
      if (row < N) v = *(const float4*)&x[(size_t)row * 128 + kc * 32 + k4 * 4];
      xs_t[k4 * 4 + 0][r] = v.x;
      xs_t[k4 * 4 + 1][r] = v.y;
      xs_t[k4 * 4 + 2][r] = v.z;
      xs_t[k4 * 4 + 3][r] = v.w;
    }
    // stage W chunk: 32 k x 64 cols = 512 float4, 4 per thread
#pragma unroll
    for (int j = 0; j < 4; ++j) {
      int f = tid + j * 128;
      int kr = f >> 4, c4 = f & 15;
      *(float4*)&Wl[kr][c4 * 4] =
          *(const float4*)&Wm[(size_t)(kc * 32 + kr) * 128 + ch * 64 + c4 * 4];
    }
    __syncthreads();
#pragma unroll 4
    for (int k = 0; k < 32; ++k) {
      float wv[8], xv[8];
      *(float4*)&wv[0] = *(const float4*)&Wl[k][tx * 8];
      *(float4*)&wv[4] = *(const float4*)&Wl[k][tx * 8 + 4];
      *(float4*)&xv[0] = *(const float4*)&xs_t[k][ty * 8];
      *(float4*)&xv[4] = *(const float4*)&xs_t[k][ty * 8 + 4];
#pragma unroll
      for (int r = 0; r < 8; ++r)
#pragma unroll
        for (int c = 0; c < 8; ++c) acc[r][c] = fmaf(xv[r], wv[c], acc[r][c]);
    }
  }

  float att_s[8], att_d[8];
#pragma unroll
  for (int c = 0; c < 8; ++c) {
    att_s[c] = att_src[ch * 64 + tx * 8 + c];
    att_d[c] = att_dst[ch * 64 + tx * 8 + c];
  }

#pragma unroll
  for (int r = 0; r < 8; ++r) {
    int row = row0 + ty * 8 + r;
    bool ok = row < N;
    float vs = 0.f, vd = 0.f;
#pragma unroll
    for (int c = 0; c < 8; ++c) {
      vs += acc[r][c] * att_s[c];
      vd += acc[r][c] * att_d[c];
    }
    // reduce across the 4 tx-lanes (32 cols) of each head
    vs += __shfl_xor(vs, 1);
    vs += __shfl_xor(vs, 2);
    vd += __shfl_xor(vd, 1);
    vd += __shfl_xor(vd, 2);
    if (ok) {
      *(float4*)&xw[(size_t)row * 128 + ch * 64 + tx * 8] =
          make_float4(acc[r][0], acc[r][1], acc[r][2], acc[r][3]);
      *(float4*)&xw[(size_t)row * 128 + ch * 64 + tx * 8 + 4] =
          make_float4(acc[r][4], acc[r][5], acc[r][6], acc[r][7]);
      if ((tx & 3) == 0) {
        // pre-scale by log2(e): leaky_relu commutes with positive scaling
        a_src[row * 4 + ch * 2 + (tx >> 2)] = vs * LOG2E;
        a_dst[row * 4 + ch * 2 + (tx >> 2)] = vd * LOG2E;
      }
    }
  }
}

// ---------------- K2: CSR build ----------------
__global__ __launch_bounds__(256) void k_hist(const int* __restrict__ ei, int E,
                                              int N, int* __restrict__ deg) {
  int e = blockIdx.x * 256 + threadIdx.x;
  if (e >= E + N) return;
  int dst = (e < E) ? ei[E + e] : (e - E);
  atomicAdd(&deg[dst], 1);
}

__global__ __launch_bounds__(256) void k_scan1(const int* __restrict__ deg,
                                               int* __restrict__ offs,
                                               int* __restrict__ part, int N) {
  __shared__ int lds[4];
  int i = blockIdx.x * 256 + threadIdx.x;
  int v = (i < N) ? deg[i] : 0;
  int s = blockInclScan(v, threadIdx.x, lds);
  if (i < N) offs[i + 1] = s;
  if (threadIdx.x == 255) part[blockIdx.x] = s;
}

__global__ __launch_bounds__(256) void k_scan2(int* part, int B) {
  __shared__ int lds[4];
  __shared__ int basesh;
  int tid = threadIdx.x;
  int base = 0;
  for (int c0 = 0; c0 < B; c0 += 256) {
    int i = c0 + tid;
    int v = (i < B) ? part[i] : 0;
    int sv = blockInclScan(v, tid, lds);
    if (i < B) part[i] = base + sv;
    if (tid == 255) basesh = base + sv;
    __syncthreads();
    base = basesh;
    __syncthreads();
  }
}

__global__ __launch_bounds__(256) void k_scan3(const int* __restrict__ deg,
                                               int* __restrict__ offs,
                                               const int* __restrict__ part,
                                               int* __restrict__ cursor, int N) {
  int i = blockIdx.x * 256 + threadIdx.x;
  int add = blockIdx.x ? part[blockIdx.x - 1] : 0;
  if (i < N) {
    int inc = offs[i + 1] + add;
    offs[i + 1] = inc;
    cursor[i] = inc - deg[i];  // exclusive prefix = segment start
  }
  if (i == 0) offs[0] = 0;
}

__global__ __launch_bounds__(256) void k_scatter(const int* __restrict__ ei, int E,
                                                 int N, int* __restrict__ cursor,
                                                 int* __restrict__ srcs) {
  int e = blockIdx.x * 256 + threadIdx.x;
  if (e >= E + N) return;
  int src, dst;
  if (e < E) {
    src = ei[e];
    dst = ei[E + e];
  } else {
    src = e - E;
    dst = e - E;
  }
  int pos = atomicAdd(&cursor[dst], 1);
  srcs[pos] = src;
}

// ---------------- K3: per-node segment softmax + aggregate ----------------
// one 64-lane wave per destination node; lane covers 2 channels.
// Logits already scaled by log2(e); p = 2^leaky(t) via v_exp_f32.
// No max subtraction (logits bounded, ratio identical) -> 1 exp, 2 fma / edge.
__global__ __launch_bounds__(256) void k_agg(
    const int* __restrict__ srcs, const int* __restrict__ offs,
    const float* __restrict__ xw, const float* __restrict__ asrc,
    const float* __restrict__ adst, const float* __restrict__ bias,
    float* __restrict__ out, int N) {
  int gw = (int)(((size_t)blockIdx.x * blockDim.x + threadIdx.x) >> 6);
  int lane = threadIdx.x & 63;
  if (gw >= N) return;
  int beg = offs[gw];
  int end = offs[gw + 1];
  int h = lane >> 4;  // head of this lane's 2 channels (cols 2l, 2l+1)
  float ad = adst[gw * 4 + h];
  const float* xr = xw + lane * 2;
  float2 bv = *(const float2*)&bias[lane * 2];

  float s0 = 0.f, s1 = 0.f;
  float a00 = 0.f, a01 = 0.f, a10 = 0.f, a11 = 0.f;
  int i = beg;
  for (; i + 2 <= end; i += 2) {
    int src0 = srcs[i];
    int src1 = srcs[i + 1];
    float t0 = asrc[src0 * 4 + h] + ad;
    float t1 = asrc[src1 * 4 + h] + ad;
    float p0 = fast_exp2(fmaxf(t0, 0.2f * t0));  // leaky_relu(z)=max(z,.2z)
    float p1 = fast_exp2(fmaxf(t1, 0.2f * t1));
    float2 x0 = *(const float2*)(xr + (size_t)src0 * 128);
    float2 x1 = *(const float2*)(xr + (size_t)src1 * 128);
    s0 += p0;
    s1 += p1;
    a00 = fmaf(p0, x0.x, a00);
    a01 = fmaf(p0, x0.y, a01);
    a10 = fmaf(p1, x1.x, a10);
    a11 = fmaf(p1, x1.y, a11);
  }
  if (i < end) {
    int src = srcs[i];
    float t = asrc[src * 4 + h] + ad;
    float p = fast_exp2(fmaxf(t, 0.2f * t));
    float2 xv = *(const float2*)(xr + (size_t)src * 128);
    s0 += p;
    a00 = fmaf(p, xv.x, a00);
    a01 = fmaf(p, xv.y, a01);
  }
  float inv = 1.f / (s0 + s1);
  float o0 = fmaf(a00 + a10, inv, bv.x);
  float o1 = fmaf(a01 + a11, inv, bv.y);
  o0 = o0 > 0.f ? o0 : expm1f(o0);  // ELU
  o1 = o1 > 0.f ? o1 : expm1f(o1);
  *(float2*)&out[(size_t)gw * 128 + lane * 2] = make_float2(o0, o1);
}

// ---------------------------------------------------------------------------
extern "C" void kernel_launch(void* const* d_in, const int* in_sizes, int n_in,
                              void* d_out, int out_size, void* d_ws, size_t ws_size,
                              hipStream_t stream) {
  const float* x = (const float*)d_in[0];
  const int* ei = (const int*)d_in[1];  // [2,E] int
  const float* Wm = (const float*)d_in[2];
  const float* att_src = (const float*)d_in[3];
  const float* att_dst = (const float*)d_in[4];
  const float* bias = (const float*)d_in[5];
  float* out = (float*)d_out;

  const int N = in_sizes[0] / 128;
  const int E = in_sizes[1] / 2;
  const int EL = E + N;  // edges + self loops

  size_t off = 0;
  auto carve = [&](size_t bytes) -> void* {
    void* p = (char*)d_ws + off;
    off += (bytes + 255) & ~(size_t)255;
    return p;
  };
  float* xw = (float*)carve((size_t)N * 128 * 4);
  float* a_src = (float*)carve((size_t)N * 4 * 4);
  float* a_dst = (float*)carve((size_t)N * 4 * 4);
  int* deg = (int*)carve((size_t)N * 4);
  int* offs = (int*)carve((size_t)(N + 1) * 4);
  int* cursor = (int*)carve((size_t)N * 4);
  int* part = (int*)carve(4096);
  int* srcs = (int*)carve((size_t)EL * 4);

  hipMemsetAsync(deg, 0, (size_t)N * 4, stream);

  dim3 g1((N + 127) / 128, 2);
  k_gemm<<<g1, 128, 0, stream>>>(x, Wm, att_src, att_dst, xw, a_src, a_dst, N);

  int ebl = (EL + 255) / 256;
  k_hist<<<ebl, 256, 0, stream>>>(ei, E, N, deg);

  int B = (N + 255) / 256;
  k_scan1<<<B, 256, 0, stream>>>(deg, offs, part, N);
  k_scan2<<<1, 256, 0, stream>>>(part, B);
  k_scan3<<<B, 256, 0, stream>>>(deg, offs, part, cursor, N);

  k_scatter<<<ebl, 256, 0, stream>>>(ei, E, N, cursor, srcs);

  int abl = (int)(((size_t)N * 64 + 255) / 256);
  k_agg<<<abl, 256, 0, stream>>>(srcs, offs, xw, a_src, a_dst, bias, out, N);
}

// Round 4
// 360.385 us; speedup vs baseline: 1.2981x; 1.1699x over previous
//
#include <hip/hip_runtime.h>
#include <cmath>

// ---------------------------------------------------------------------------
// GAT layer: N=100000 nodes, IN=128, OUT=32, H=4 (H*OUT=128), E=1.6M edges.
// Pipeline:
//   K1  k_gemm    : xw = x@W  [N,128] stored as packed bf16 (uint per 2 ch),
//                   fused a_src/a_dst logits [N,4] pre-scaled by log2(e)
//   K2a k_hist    : histogram of dst degrees (incl. self loops)
//   K2b scan1/2/3 : exclusive prefix sum -> CSR offsets + cursor
//   K2c k_scatter : bucket src indices by dst (CSR edge list)
//   K3  k_agg     : per-dst-node wave: segment softmax (no max subtraction --
//                   logits bounded, ratio identical) + weighted aggregation of
//                   bf16 xw[src], bias + ELU, nontemporal write of out row
// ---------------------------------------------------------------------------

#define LOG2E 1.44269504088896340736f

typedef float f32x2 __attribute__((ext_vector_type(2)));

__device__ __forceinline__ float fast_exp2(float x) {
#if __has_builtin(__builtin_amdgcn_exp2f)
  return __builtin_amdgcn_exp2f(x);
#else
  return exp2f(x);
#endif
}

// f32 -> bf16 (round-to-nearest-even), returned in low 16 bits
__device__ __forceinline__ unsigned bf16_rne(float f) {
  unsigned u = __float_as_uint(f);
  return (u + 0x7fffu + ((u >> 16) & 1u)) >> 16;
}
__device__ __forceinline__ float bf_lo(unsigned v) {
  return __uint_as_float(v << 16);
}
__device__ __forceinline__ float bf_hi(unsigned v) {
  return __uint_as_float(v & 0xffff0000u);
}

__device__ __forceinline__ int blockInclScan(int v, int tid, int* lds) {
  int lane = tid & 63;
  int wid = tid >> 6;
#pragma unroll
  for (int off = 1; off < 64; off <<= 1) {
    int t = __shfl_up(v, off);
    if (lane >= off) v += t;
  }
  if (lane == 63) lds[wid] = v;
  __syncthreads();
  int add = 0;
  for (int i = 0; i < wid; ++i) add += lds[i];
  v += add;
  __syncthreads();
  return v;
}

// ---------------- K1: GEMM + attention logits ----------------
// grid (ceil(N/128), 2), block 128.  tx = tid&7, ty = tid>>3.
// Block: 128 rows x 64 cols (one col-half = 2 heads), k-chunked by 32,
// 8x8 register tile per thread.  x staged K-MAJOR for clean ds_read_b128.
// Output packed bf16 (2 ch per uint).
__global__ __launch_bounds__(128) void k_gemm(
    const float* __restrict__ x, const float* __restrict__ Wm,
    const float* __restrict__ att_src, const float* __restrict__ att_dst,
    unsigned* __restrict__ xwb, float* __restrict__ a_src,
    float* __restrict__ a_dst, int N) {
  __shared__ float xs_t[32][132];
  __shared__ float Wl[32][64];
  const int tid = threadIdx.x;
  const int tx = tid & 7;
  const int ty = tid >> 3;
  const int ch = blockIdx.y;
  const int row0 = blockIdx.x * 128;

  float acc[8][8];
#pragma unroll
  for (int r = 0; r < 8; ++r)
#pragma unroll
    for (int c = 0; c < 8; ++c) acc[r][c] = 0.f;

  for (int kc = 0; kc < 4; ++kc) {
    __syncthreads();
#pragma unroll
    for (int j = 0; j < 8; ++j) {
      int f = tid + j * 128;
      int r = f >> 3, k4 = f & 7;
      int row = row0 + r;
      float4 v = make_float4(0.f, 0.f, 0.f, 0.f);
      if (row < N) v = *(const float4*)&x[(size_t)row * 128 + kc * 32 + k4 * 4];
      xs_t[k4 * 4 + 0][r] = v.x;
      xs_t[k4 * 4 + 1][r] = v.y;
      xs_t[k4 * 4 + 2][r] = v.z;
      xs_t[k4 * 4 + 3][r] = v.w;
    }
#pragma unroll
    for (int j = 0; j < 4; ++j) {
      int f = tid + j * 128;
      int kr = f >> 4, c4 = f & 15;
      *(float4*)&Wl[kr][c4 * 4] =
          *(const float4*)&Wm[(size_t)(kc * 32 + kr) * 128 + ch * 64 + c4 * 4];
    }
    __syncthreads();
#pragma unroll 4
    for (int k = 0; k < 32; ++k) {
      float wv[8], xv[8];
      *(float4*)&wv[0] = *(const float4*)&Wl[k][tx * 8];
      *(float4*)&wv[4] = *(const float4*)&Wl[k][tx * 8 + 4];
      *(float4*)&xv[0] = *(const float4*)&xs_t[k][ty * 8];
      *(float4*)&xv[4] = *(const float4*)&xs_t[k][ty * 8 + 4];
#pragma unroll
      for (int r = 0; r < 8; ++r)
#pragma unroll
        for (int c = 0; c < 8; ++c) acc[r][c] = fmaf(xv[r], wv[c], acc[r][c]);
    }
  }

  float att_s[8], att_d[8];
#pragma unroll
  for (int c = 0; c < 8; ++c) {
    att_s[c] = att_src[ch * 64 + tx * 8 + c];
    att_d[c] = att_dst[ch * 64 + tx * 8 + c];
  }

#pragma unroll
  for (int r = 0; r < 8; ++r) {
    int row = row0 + ty * 8 + r;
    bool ok = row < N;
    float vs = 0.f, vd = 0.f;
#pragma unroll
    for (int c = 0; c < 8; ++c) {
      vs += acc[r][c] * att_s[c];
      vd += acc[r][c] * att_d[c];
    }
    vs += __shfl_xor(vs, 1);
    vs += __shfl_xor(vs, 2);
    vd += __shfl_xor(vd, 1);
    vd += __shfl_xor(vd, 2);
    if (ok) {
      uint4 pk;
      pk.x = bf16_rne(acc[r][0]) | (bf16_rne(acc[r][1]) << 16);
      pk.y = bf16_rne(acc[r][2]) | (bf16_rne(acc[r][3]) << 16);
      pk.z = bf16_rne(acc[r][4]) | (bf16_rne(acc[r][5]) << 16);
      pk.w = bf16_rne(acc[r][6]) | (bf16_rne(acc[r][7]) << 16);
      *(uint4*)&xwb[(size_t)row * 64 + ch * 32 + tx * 4] = pk;
      if ((tx & 3) == 0) {
        a_src[row * 4 + ch * 2 + (tx >> 2)] = vs * LOG2E;
        a_dst[row * 4 + ch * 2 + (tx >> 2)] = vd * LOG2E;
      }
    }
  }
}

// ---------------- K2: CSR build ----------------
__global__ __launch_bounds__(256) void k_hist(const int* __restrict__ ei, int E,
                                              int N, int* __restrict__ deg) {
  int e = blockIdx.x * 256 + threadIdx.x;
  if (e >= E + N) return;
  int dst = (e < E) ? ei[E + e] : (e - E);
  atomicAdd(&deg[dst], 1);
}

__global__ __launch_bounds__(256) void k_scan1(const int* __restrict__ deg,
                                               int* __restrict__ offs,
                                               int* __restrict__ part, int N) {
  __shared__ int lds[4];
  int i = blockIdx.x * 256 + threadIdx.x;
  int v = (i < N) ? deg[i] : 0;
  int s = blockInclScan(v, threadIdx.x, lds);
  if (i < N) offs[i + 1] = s;
  if (threadIdx.x == 255) part[blockIdx.x] = s;
}

__global__ __launch_bounds__(256) void k_scan2(int* part, int B) {
  __shared__ int lds[4];
  __shared__ int basesh;
  int tid = threadIdx.x;
  int base = 0;
  for (int c0 = 0; c0 < B; c0 += 256) {
    int i = c0 + tid;
    int v = (i < B) ? part[i] : 0;
    int sv = blockInclScan(v, tid, lds);
    if (i < B) part[i] = base + sv;
    if (tid == 255) basesh = base + sv;
    __syncthreads();
    base = basesh;
    __syncthreads();
  }
}

__global__ __launch_bounds__(256) void k_scan3(const int* __restrict__ deg,
                                               int* __restrict__ offs,
                                               const int* __restrict__ part,
                                               int* __restrict__ cursor, int N) {
  int i = blockIdx.x * 256 + threadIdx.x;
  int add = blockIdx.x ? part[blockIdx.x - 1] : 0;
  if (i < N) {
    int inc = offs[i + 1] + add;
    offs[i + 1] = inc;
    cursor[i] = inc - deg[i];
  }
  if (i == 0) offs[0] = 0;
}

__global__ __launch_bounds__(256) void k_scatter(const int* __restrict__ ei, int E,
                                                 int N, int* __restrict__ cursor,
                                                 int* __restrict__ srcs) {
  int e = blockIdx.x * 256 + threadIdx.x;
  if (e >= E + N) return;
  int src, dst;
  if (e < E) {
    src = ei[e];
    dst = ei[E + e];
  } else {
    src = e - E;
    dst = e - E;
  }
  int pos = atomicAdd(&cursor[dst], 1);
  srcs[pos] = src;
}

// ---------------- K3: per-node segment softmax + aggregate ----------------
// one 64-lane wave per destination node; lane covers 2 bf16 channels (4B).
// 4-way unrolled edge loop: 4 independent gather chains in flight.
__global__ __launch_bounds__(256) void k_agg(
    const int* __restrict__ srcs, const int* __restrict__ offs,
    const unsigned* __restrict__ xwb, const float* __restrict__ asrc,
    const float* __restrict__ adst, const float* __restrict__ bias,
    float* __restrict__ out, int N) {
  int gw = (int)(((size_t)blockIdx.x * blockDim.x + threadIdx.x) >> 6);
  int lane = threadIdx.x & 63;
  if (gw >= N) return;
  int beg = offs[gw];
  int end = offs[gw + 1];
  int h = lane >> 4;
  float ad = adst[gw * 4 + h];
  const unsigned* xr = xwb + lane;
  float2 bv = *(const float2*)&bias[lane * 2];

  float s0 = 0.f, s1 = 0.f, s2 = 0.f, s3 = 0.f;
  float a00 = 0.f, a01 = 0.f, a10 = 0.f, a11 = 0.f;
  float a20 = 0.f, a21 = 0.f, a30 = 0.f, a31 = 0.f;
  int i = beg;
  for (; i + 4 <= end; i += 4) {
    int e0 = srcs[i], e1 = srcs[i + 1], e2 = srcs[i + 2], e3 = srcs[i + 3];
    unsigned v0 = xr[(size_t)e0 * 64];
    unsigned v1 = xr[(size_t)e1 * 64];
    unsigned v2 = xr[(size_t)e2 * 64];
    unsigned v3 = xr[(size_t)e3 * 64];
    float t0 = asrc[e0 * 4 + h] + ad;
    float t1 = asrc[e1 * 4 + h] + ad;
    float t2 = asrc[e2 * 4 + h] + ad;
    float t3 = asrc[e3 * 4 + h] + ad;
    float p0 = fast_exp2(fmaxf(t0, 0.2f * t0));
    float p1 = fast_exp2(fmaxf(t1, 0.2f * t1));
    float p2 = fast_exp2(fmaxf(t2, 0.2f * t2));
    float p3 = fast_exp2(fmaxf(t3, 0.2f * t3));
    s0 += p0; s1 += p1; s2 += p2; s3 += p3;
    a00 = fmaf(p0, bf_lo(v0), a00); a01 = fmaf(p0, bf_hi(v0), a01);
    a10 = fmaf(p1, bf_lo(v1), a10); a11 = fmaf(p1, bf_hi(v1), a11);
    a20 = fmaf(p2, bf_lo(v2), a20); a21 = fmaf(p2, bf_hi(v2), a21);
    a30 = fmaf(p3, bf_lo(v3), a30); a31 = fmaf(p3, bf_hi(v3), a31);
  }
  for (; i < end; ++i) {
    int e0 = srcs[i];
    unsigned v0 = xr[(size_t)e0 * 64];
    float t0 = asrc[e0 * 4 + h] + ad;
    float p0 = fast_exp2(fmaxf(t0, 0.2f * t0));
    s0 += p0;
    a00 = fmaf(p0, bf_lo(v0), a00);
    a01 = fmaf(p0, bf_hi(v0), a01);
  }
  float inv = 1.f / ((s0 + s1) + (s2 + s3));
  float o0 = fmaf((a00 + a10) + (a20 + a30), inv, bv.x);
  float o1 = fmaf((a01 + a11) + (a21 + a31), inv, bv.y);
  o0 = o0 > 0.f ? o0 : expm1f(o0);  // ELU
  o1 = o1 > 0.f ? o1 : expm1f(o1);
  f32x2 o;
  o.x = o0;
  o.y = o1;
  __builtin_nontemporal_store(o, (f32x2*)&out[(size_t)gw * 128 + lane * 2]);
}

// ---------------------------------------------------------------------------
extern "C" void kernel_launch(void* const* d_in, const int* in_sizes, int n_in,
                              void* d_out, int out_size, void* d_ws, size_t ws_size,
                              hipStream_t stream) {
  const float* x = (const float*)d_in[0];
  const int* ei = (const int*)d_in[1];
  const float* Wm = (const float*)d_in[2];
  const float* att_src = (const float*)d_in[3];
  const float* att_dst = (const float*)d_in[4];
  const float* bias = (const float*)d_in[5];
  float* out = (float*)d_out;

  const int N = in_sizes[0] / 128;
  const int E = in_sizes[1] / 2;
  const int EL = E + N;

  size_t off = 0;
  auto carve = [&](size_t bytes) -> void* {
    void* p = (char*)d_ws + off;
    off += (bytes + 255) & ~(size_t)255;
    return p;
  };
  unsigned* xwb = (unsigned*)carve((size_t)N * 64 * 4);  // bf16-packed [N][64]
  float* a_src = (float*)carve((size_t)N * 4 * 4);
  float* a_dst = (float*)carve((size_t)N * 4 * 4);
  int* deg = (int*)carve((size_t)N * 4);
  int* offs = (int*)carve((size_t)(N + 1) * 4);
  int* cursor = (int*)carve((size_t)N * 4);
  int* part = (int*)carve(4096);
  int* srcs = (int*)carve((size_t)EL * 4);

  (void)hipMemsetAsync(deg, 0, (size_t)N * 4, stream);

  dim3 g1((N + 127) / 128, 2);
  k_gemm<<<g1, 128, 0, stream>>>(x, Wm, att_src, att_dst, xwb, a_src, a_dst, N);

  int ebl = (EL + 255) / 256;
  k_hist<<<ebl, 256, 0, stream>>>(ei, E, N, deg);

  int B = (N + 255) / 256;
  k_scan1<<<B, 256, 0, stream>>>(deg, offs, part, N);
  k_scan2<<<1, 256, 0, stream>>>(part, B);
  k_scan3<<<B, 256, 0, stream>>>(deg, offs, part, cursor, N);

  k_scatter<<<ebl, 256, 0, stream>>>(ei, E, N, cursor, srcs);

  int abl = (int)(((size_t)N * 64 + 255) / 256);
  k_agg<<<abl, 256, 0, stream>>>(srcs, offs, xwb, a_src, a_dst, bias, out, N);
}

// Round 5
// 198.200 us; speedup vs baseline: 2.3603x; 1.8183x over previous
//
#include <hip/hip_runtime.h>
#include <cmath>

// ---------------------------------------------------------------------------
// GAT layer: N=100000 nodes, IN=128, OUT=32, H=4 (H*OUT=128), E=1.6M edges.
// Pipeline:
//   K1  k_gemm   : xw = x@W [N,128] packed bf16, fused a_src/a_dst logits
//   CSR build (two-level bucketed, LDS-atomic only, dense global traffic):
//     p1_hist    : per-block LDS histogram over NB=ceil(N/256) dst-buckets
//     p2a_bsum   : bucket totals
//     p2b_bscan  : exclusive scan of bucket totals -> bucket bases
//     p2c_brow   : per-bucket scan across blocks -> absolute block cursors
//     p3_part    : scatter packed (dloc<<24|src) into bucket segments (LDS cur)
//     p4_local   : per-bucket: LDS degree hist + scan -> offs, scatter srcs
//   K3  k_agg    : per-dst-node wave: segment softmax + weighted aggregation
//                  of bf16 xw[src], bias + ELU, nontemporal row write
// ---------------------------------------------------------------------------

#define LOG2E 1.44269504088896340736f

typedef float f32x2 __attribute__((ext_vector_type(2)));

__device__ __forceinline__ float fast_exp2(float x) {
#if __has_builtin(__builtin_amdgcn_exp2f)
  return __builtin_amdgcn_exp2f(x);
#else
  return exp2f(x);
#endif
}

__device__ __forceinline__ unsigned bf16_rne(float f) {
  unsigned u = __float_as_uint(f);
  return (u + 0x7fffu + ((u >> 16) & 1u)) >> 16;
}
__device__ __forceinline__ float bf_lo(unsigned v) {
  return __uint_as_float(v << 16);
}
__device__ __forceinline__ float bf_hi(unsigned v) {
  return __uint_as_float(v & 0xffff0000u);
}

// inclusive block scan; lds must hold >= blockDim/64 ints
__device__ __forceinline__ int blockInclScan(int v, int tid, int* lds) {
  int lane = tid & 63;
  int wid = tid >> 6;
#pragma unroll
  for (int off = 1; off < 64; off <<= 1) {
    int t = __shfl_up(v, off);
    if (lane >= off) v += t;
  }
  if (lane == 63) lds[wid] = v;
  __syncthreads();
  int add = 0;
  for (int i = 0; i < wid; ++i) add += lds[i];
  v += add;
  __syncthreads();
  return v;
}

// ---------------- K1: GEMM + attention logits ----------------
__global__ __launch_bounds__(128) void k_gemm(
    const float* __restrict__ x, const float* __restrict__ Wm,
    const float* __restrict__ att_src, const float* __restrict__ att_dst,
    unsigned* __restrict__ xwb, float* __restrict__ a_src,
    float* __restrict__ a_dst, int N) {
  __shared__ float xs_t[32][132];
  __shared__ float Wl[32][64];
  const int tid = threadIdx.x;
  const int tx = tid & 7;
  const int ty = tid >> 3;
  const int ch = blockIdx.y;
  const int row0 = blockIdx.x * 128;

  float acc[8][8];
#pragma unroll
  for (int r = 0; r < 8; ++r)
#pragma unroll
    for (int c = 0; c < 8; ++c) acc[r][c] = 0.f;

  for (int kc = 0; kc < 4; ++kc) {
    __syncthreads();
#pragma unroll
    for (int j = 0; j < 8; ++j) {
      int f = tid + j * 128;
      int r = f >> 3, k4 = f & 7;
      int row = row0 + r;
      float4 v = make_float4(0.f, 0.f, 0.f, 0.f);
      if (row < N) v = *(const float4*)&x[(size_t)row * 128 + kc * 32 + k4 * 4];
      xs_t[k4 * 4 + 0][r] = v.x;
      xs_t[k4 * 4 + 1][r] = v.y;
      xs_t[k4 * 4 + 2][r] = v.z;
      xs_t[k4 * 4 + 3][r] = v.w;
    }
#pragma unroll
    for (int j = 0; j < 4; ++j) {
      int f = tid + j * 128;
      int kr = f >> 4, c4 = f & 15;
      *(float4*)&Wl[kr][c4 * 4] =
          *(const float4*)&Wm[(size_t)(kc * 32 + kr) * 128 + ch * 64 + c4 * 4];
    }
    __syncthreads();
#pragma unroll 4
    for (int k = 0; k < 32; ++k) {
      float wv[8], xv[8];
      *(float4*)&wv[0] = *(const float4*)&Wl[k][tx * 8];
      *(float4*)&wv[4] = *(const float4*)&Wl[k][tx * 8 + 4];
      *(float4*)&xv[0] = *(const float4*)&xs_t[k][ty * 8];
      *(float4*)&xv[4] = *(const float4*)&xs_t[k][ty * 8 + 4];
#pragma unroll
      for (int r = 0; r < 8; ++r)
#pragma unroll
        for (int c = 0; c < 8; ++c) acc[r][c] = fmaf(xv[r], wv[c], acc[r][c]);
    }
  }

  float att_s[8], att_d[8];
#pragma unroll
  for (int c = 0; c < 8; ++c) {
    att_s[c] = att_src[ch * 64 + tx * 8 + c];
    att_d[c] = att_dst[ch * 64 + tx * 8 + c];
  }

#pragma unroll
  for (int r = 0; r < 8; ++r) {
    int row = row0 + ty * 8 + r;
    bool ok = row < N;
    float vs = 0.f, vd = 0.f;
#pragma unroll
    for (int c = 0; c < 8; ++c) {
      vs += acc[r][c] * att_s[c];
      vd += acc[r][c] * att_d[c];
    }
    vs += __shfl_xor(vs, 1);
    vs += __shfl_xor(vs, 2);
    vd += __shfl_xor(vd, 1);
    vd += __shfl_xor(vd, 2);
    if (ok) {
      uint4 pk;
      pk.x = bf16_rne(acc[r][0]) | (bf16_rne(acc[r][1]) << 16);
      pk.y = bf16_rne(acc[r][2]) | (bf16_rne(acc[r][3]) << 16);
      pk.z = bf16_rne(acc[r][4]) | (bf16_rne(acc[r][5]) << 16);
      pk.w = bf16_rne(acc[r][6]) | (bf16_rne(acc[r][7]) << 16);
      *(uint4*)&xwb[(size_t)row * 64 + ch * 32 + tx * 4] = pk;
      if ((tx & 3) == 0) {
        a_src[row * 4 + ch * 2 + (tx >> 2)] = vs * LOG2E;
        a_dst[row * 4 + ch * 2 + (tx >> 2)] = vd * LOG2E;
      }
    }
  }
}

// ---------------- bucketed CSR build ----------------
// bucket(dst) = dst >> 8 (256 dst per bucket). NB = ceil(N/256).
// CHUNK = 4096 edges per partition block; NBLK = ceil(EL/4096).
#define CHUNK 4096

// P1: per-block histogram over buckets -> bh[b*NBLK + blk]
__global__ __launch_bounds__(256) void p1_hist(const int* __restrict__ ei, int E,
                                               int EL, int NB, int NBLK,
                                               int* __restrict__ bh) {
  __shared__ int lh[512];
  int tid = threadIdx.x;
  lh[tid] = 0;
  lh[tid + 256] = 0;
  __syncthreads();
  int base_e = blockIdx.x * CHUNK;
#pragma unroll
  for (int j = 0; j < CHUNK / 256; ++j) {
    int e = base_e + j * 256 + tid;
    if (e < EL) {
      int dst = (e < E) ? ei[E + e] : (e - E);
      atomicAdd(&lh[dst >> 8], 1);
    }
  }
  __syncthreads();
  for (int b = tid; b < NB; b += 256) bh[(size_t)b * NBLK + blockIdx.x] = lh[b];
}

// P2a: bucket totals
__global__ __launch_bounds__(256) void p2a_bsum(const int* __restrict__ bh,
                                                int* __restrict__ btot, int NBLK) {
  __shared__ int red[256];
  int b = blockIdx.x;
  int s = 0;
  for (int j = threadIdx.x; j < NBLK; j += 256) s += bh[(size_t)b * NBLK + j];
  red[threadIdx.x] = s;
  __syncthreads();
  for (int st = 128; st > 0; st >>= 1) {
    if (threadIdx.x < st) red[threadIdx.x] += red[threadIdx.x + st];
    __syncthreads();
  }
  if (threadIdx.x == 0) btot[b] = red[0];
}

// P2b: exclusive scan of bucket totals -> bbase  (single block, 512 threads)
__global__ __launch_bounds__(512) void p2b_bscan(const int* __restrict__ btot,
                                                 int* __restrict__ bbase, int NB) {
  __shared__ int lds[8];
  int i = threadIdx.x;
  int v = (i < NB) ? btot[i] : 0;
  int incl = blockInclScan(v, i, lds);
  if (i < NB) bbase[i] = incl - v;
}

// P2c: per-bucket exclusive scan across blocks (row of bh), + bbase
// NBLK <= 512: two 256-chunks.
__global__ __launch_bounds__(256) void p2c_brow(int* __restrict__ bh,
                                                const int* __restrict__ bbase,
                                                int NBLK) {
  __shared__ int lds[4];
  __shared__ int ctot;
  int b = blockIdx.x;
  int tid = threadIdx.x;
  int base = bbase[b];
  int v0 = (tid < NBLK) ? bh[(size_t)b * NBLK + tid] : 0;
  int incl0 = blockInclScan(v0, tid, lds);
  if (tid < NBLK) bh[(size_t)b * NBLK + tid] = base + incl0 - v0;
  if (tid == 255) ctot = incl0;
  __syncthreads();
  int base1 = base + ctot;
  int j = 256 + tid;
  int v1 = (j < NBLK) ? bh[(size_t)b * NBLK + j] : 0;
  int incl1 = blockInclScan(v1, tid, lds);
  if (j < NBLK) bh[(size_t)b * NBLK + j] = base1 + incl1 - v1;
}

// P3: partition edges into bucket segments, packed word (dloc<<24 | src)
__global__ __launch_bounds__(256) void p3_part(const int* __restrict__ ei, int E,
                                               int EL, int NB, int NBLK,
                                               const int* __restrict__ bh,
                                               unsigned* __restrict__ tmp) {
  __shared__ int lc[512];
  int tid = threadIdx.x;
  for (int b = tid; b < NB; b += 256) lc[b] = bh[(size_t)b * NBLK + blockIdx.x];
  __syncthreads();
  int base_e = blockIdx.x * CHUNK;
#pragma unroll
  for (int j = 0; j < CHUNK / 256; ++j) {
    int e = base_e + j * 256 + tid;
    if (e < EL) {
      int src, dst;
      if (e < E) {
        src = ei[e];
        dst = ei[E + e];
      } else {
        src = e - E;
        dst = e - E;
      }
      int pos = atomicAdd(&lc[dst >> 8], 1);
      tmp[pos] = ((unsigned)(dst & 255) << 24) | (unsigned)src;
    }
  }
}

// P4: per-bucket local CSR: LDS degree hist + scan -> offs, scatter srcs
__global__ __launch_bounds__(256) void p4_local(const unsigned* __restrict__ tmp,
                                                const int* __restrict__ bbase,
                                                const int* __restrict__ btot,
                                                int N, int NB, int EL,
                                                int* __restrict__ offs,
                                                int* __restrict__ srcs) {
  __shared__ int deg[256];
  __shared__ int cur[256];
  __shared__ int lds[4];
  int b = blockIdx.x;
  int tid = threadIdx.x;
  int beg = bbase[b];
  int end = beg + btot[b];
  deg[tid] = 0;
  __syncthreads();
  for (int k = beg + tid; k < end; k += 256) {
    unsigned w = tmp[k];
    atomicAdd(&deg[w >> 24], 1);
  }
  __syncthreads();
  int v = deg[tid];
  int incl = blockInclScan(v, tid, lds);
  int excl = incl - v;
  int idx = b * 256 + tid;
  if (idx < N) offs[idx] = beg + excl;
  cur[tid] = beg + excl;
  if (b == NB - 1 && tid == 0) offs[N] = EL;
  __syncthreads();
  for (int k = beg + tid; k < end; k += 256) {
    unsigned w = tmp[k];
    int pos = atomicAdd(&cur[w >> 24], 1);
    srcs[pos] = (int)(w & 0xFFFFFFu);
  }
}

// ---------------- K3: per-node segment softmax + aggregate ----------------
__global__ __launch_bounds__(256) void k_agg(
    const int* __restrict__ srcs, const int* __restrict__ offs,
    const unsigned* __restrict__ xwb, const float* __restrict__ asrc,
    const float* __restrict__ adst, const float* __restrict__ bias,
    float* __restrict__ out, int N) {
  int gw = (int)(((size_t)blockIdx.x * blockDim.x + threadIdx.x) >> 6);
  int lane = threadIdx.x & 63;
  if (gw >= N) return;
  int beg = offs[gw];
  int end = offs[gw + 1];
  int h = lane >> 4;
  float ad = adst[gw * 4 + h];
  const unsigned* xr = xwb + lane;
  float2 bv = *(const float2*)&bias[lane * 2];

  float s0 = 0.f, s1 = 0.f, s2 = 0.f, s3 = 0.f;
  float a00 = 0.f, a01 = 0.f, a10 = 0.f, a11 = 0.f;
  float a20 = 0.f, a21 = 0.f, a30 = 0.f, a31 = 0.f;
  int i = beg;
  for (; i + 4 <= end; i += 4) {
    int e0 = srcs[i], e1 = srcs[i + 1], e2 = srcs[i + 2], e3 = srcs[i + 3];
    unsigned v0 = xr[(size_t)e0 * 64];
    unsigned v1 = xr[(size_t)e1 * 64];
    unsigned v2 = xr[(size_t)e2 * 64];
    unsigned v3 = xr[(size_t)e3 * 64];
    float t0 = asrc[e0 * 4 + h] + ad;
    float t1 = asrc[e1 * 4 + h] + ad;
    float t2 = asrc[e2 * 4 + h] + ad;
    float t3 = asrc[e3 * 4 + h] + ad;
    float p0 = fast_exp2(fmaxf(t0, 0.2f * t0));
    float p1 = fast_exp2(fmaxf(t1, 0.2f * t1));
    float p2 = fast_exp2(fmaxf(t2, 0.2f * t2));
    float p3 = fast_exp2(fmaxf(t3, 0.2f * t3));
    s0 += p0; s1 += p1; s2 += p2; s3 += p3;
    a00 = fmaf(p0, bf_lo(v0), a00); a01 = fmaf(p0, bf_hi(v0), a01);
    a10 = fmaf(p1, bf_lo(v1), a10); a11 = fmaf(p1, bf_hi(v1), a11);
    a20 = fmaf(p2, bf_lo(v2), a20); a21 = fmaf(p2, bf_hi(v2), a21);
    a30 = fmaf(p3, bf_lo(v3), a30); a31 = fmaf(p3, bf_hi(v3), a31);
  }
  for (; i < end; ++i) {
    int e0 = srcs[i];
    unsigned v0 = xr[(size_t)e0 * 64];
    float t0 = asrc[e0 * 4 + h] + ad;
    float p0 = fast_exp2(fmaxf(t0, 0.2f * t0));
    s0 += p0;
    a00 = fmaf(p0, bf_lo(v0), a00);
    a01 = fmaf(p0, bf_hi(v0), a01);
  }
  float inv = 1.f / ((s0 + s1) + (s2 + s3));
  float o0 = fmaf((a00 + a10) + (a20 + a30), inv, bv.x);
  float o1 = fmaf((a01 + a11) + (a21 + a31), inv, bv.y);
  o0 = o0 > 0.f ? o0 : expm1f(o0);  // ELU
  o1 = o1 > 0.f ? o1 : expm1f(o1);
  f32x2 o;
  o.x = o0;
  o.y = o1;
  __builtin_nontemporal_store(o, (f32x2*)&out[(size_t)gw * 128 + lane * 2]);
}

// ---------------------------------------------------------------------------
extern "C" void kernel_launch(void* const* d_in, const int* in_sizes, int n_in,
                              void* d_out, int out_size, void* d_ws, size_t ws_size,
                              hipStream_t stream) {
  const float* x = (const float*)d_in[0];
  const int* ei = (const int*)d_in[1];
  const float* Wm = (const float*)d_in[2];
  const float* att_src = (const float*)d_in[3];
  const float* att_dst = (const float*)d_in[4];
  const float* bias = (const float*)d_in[5];
  float* out = (float*)d_out;

  const int N = in_sizes[0] / 128;
  const int E = in_sizes[1] / 2;
  const int EL = E + N;
  const int NB = (N + 255) >> 8;            // dst buckets (256 dst each)
  const int NBLK = (EL + CHUNK - 1) / CHUNK;  // partition blocks

  size_t off = 0;
  auto carve = [&](size_t bytes) -> void* {
    void* p = (char*)d_ws + off;
    off += (bytes + 255) & ~(size_t)255;
    return p;
  };
  unsigned* xwb = (unsigned*)carve((size_t)N * 64 * 4);  // bf16-packed [N][64]
  float* a_src = (float*)carve((size_t)N * 4 * 4);
  float* a_dst = (float*)carve((size_t)N * 4 * 4);
  int* offs = (int*)carve((size_t)(N + 1) * 4);
  int* srcs = (int*)carve((size_t)EL * 4);
  unsigned* tmp = (unsigned*)carve((size_t)EL * 4);
  int* bh = (int*)carve((size_t)NB * NBLK * 4);
  int* btot = (int*)carve((size_t)NB * 4);
  int* bbase = (int*)carve((size_t)NB * 4);

  dim3 g1((N + 127) / 128, 2);
  k_gemm<<<g1, 128, 0, stream>>>(x, Wm, att_src, att_dst, xwb, a_src, a_dst, N);

  p1_hist<<<NBLK, 256, 0, stream>>>(ei, E, EL, NB, NBLK, bh);
  p2a_bsum<<<NB, 256, 0, stream>>>(bh, btot, NBLK);
  p2b_bscan<<<1, 512, 0, stream>>>(btot, bbase, NB);
  p2c_brow<<<NB, 256, 0, stream>>>(bh, bbase, NBLK);
  p3_part<<<NBLK, 256, 0, stream>>>(ei, E, EL, NB, NBLK, bh, tmp);
  p4_local<<<NB, 256, 0, stream>>>(tmp, bbase, btot, N, NB, EL, offs, srcs);

  int abl = (int)(((size_t)N * 64 + 255) / 256);
  k_agg<<<abl, 256, 0, stream>>>(srcs, offs, xwb, a_src, a_dst, bias, out, N);
}